// Round 1
// 93.254 us; speedup vs baseline: 1.0243x; 1.0243x over previous
//
#include <hip/hip_runtime.h>

// DPLoss fused, v4.
// v3 issue: 256 blocks x 1024 threads = exactly 1 block/CU, statically binding
// 16 random-length rows to each CU. Per-CU byte totals vary ~14% (worst CU
// ~+38%), and the kernel waits on the unluckiest CU. Also the 4-byte memset
// is a separate ~2us fill dispatch.
//
// v4:
//  - Kernel 1: one 256-thread block (4 waves) per row -> 4096 blocks,
//    ~8 resident/CU => 2x oversubscription; the hardware dispatcher
//    rebalances dynamically as blocks retire. Plain store of the per-row
//    MSE into d_ws[row] -- no atomics, no out-zeroing needed.
//  - Kernel 2: single 1024-thread block reduces the B partials and writes
//    out[0] = mean directly (replaces the memset dispatch; still 2 dispatches
//    total, graph-capture safe).

__global__ __launch_bounds__(256) void dploss_row_kernel(
    const float* __restrict__ pred,
    const float* __restrict__ align,
    const int* __restrict__ lens,
    float* __restrict__ row_mse,
    int B, int T)
{
    const int row  = blockIdx.x;          // grid = B blocks
    const int tid  = threadIdx.x;         // 0..255
    const int lane = tid & 63;
    const int wib  = tid >> 6;            // wave in block, 0..3

    const int L = lens[row];              // block-uniform -> scalar load
    const float* __restrict__ prow = pred  + (size_t)row * T;
    const float* __restrict__ arow = align + (size_t)row * T;
    const float4* __restrict__ p4 = (const float4*)prow;
    const float4* __restrict__ a4 = (const float4*)arow;
    const int nfull = L >> 2;             // fully-valid float4 groups

    float acc = 0.0f;
    #pragma unroll 2
    for (int g = tid; g < nfull; g += 256) {
        float4 p = p4[g];
        float4 a = a4[g];
        float d0 = p.x - __logf(a.x);
        float d1 = p.y - __logf(a.y);
        float d2 = p.z - __logf(a.z);
        float d3 = p.w - __logf(a.w);
        acc += d0 * d0 + d1 * d1 + d2 * d2 + d3 * d3;
    }

    // tail: L & 3 leftover elements, one per thread (<=3 threads)
    const int rem = L & 3;
    if (tid < rem) {
        const int idx = (nfull << 2) + tid;
        float d = prow[idx] - __logf(arow[idx]);
        acc += d * d;
    }

    // wave-64 shuffle reduction
    #pragma unroll
    for (int off = 32; off > 0; off >>= 1)
        acc += __shfl_down(acc, off, 64);

    __shared__ float wsum[4];
    if (lane == 0) wsum[wib] = acc;
    __syncthreads();

    if (tid == 0) {
        float s = wsum[0] + wsum[1] + wsum[2] + wsum[3];
        row_mse[row] = s / (float)L;
    }
}

__global__ __launch_bounds__(1024) void dploss_reduce_kernel(
    const float* __restrict__ row_mse,
    float* __restrict__ out,
    int B)
{
    const int tid  = threadIdx.x;
    const int lane = tid & 63;
    const int wib  = tid >> 6;            // 0..15

    float acc = 0.0f;
    const int B4 = B >> 2;
    const float4* __restrict__ r4 = (const float4*)row_mse;
    for (int g = tid; g < B4; g += 1024) {
        float4 v = r4[g];
        acc += v.x + v.y + v.z + v.w;
    }
    // tail (B % 4)
    for (int i = (B4 << 2) + tid; i < B; i += 1024)
        acc += row_mse[i];

    #pragma unroll
    for (int off = 32; off > 0; off >>= 1)
        acc += __shfl_down(acc, off, 64);

    __shared__ float wsum[16];
    if (lane == 0) wsum[wib] = acc;
    __syncthreads();

    if (tid == 0) {
        float total = 0.0f;
        #pragma unroll
        for (int w = 0; w < 16; ++w) total += wsum[w];
        out[0] = total / (float)B;
    }
}

extern "C" void kernel_launch(void* const* d_in, const int* in_sizes, int n_in,
                              void* d_out, int out_size, void* d_ws, size_t ws_size,
                              hipStream_t stream)
{
    const float* pred  = (const float*)d_in[0];
    const float* align = (const float*)d_in[1];
    const int*   lens  = (const int*)d_in[2];

    const int B = in_sizes[2];
    const int T = in_sizes[0] / B;

    float* out     = (float*)d_out;
    float* row_mse = (float*)d_ws;        // needs B*4 bytes; ws is far larger

    dploss_row_kernel<<<B, 256, 0, stream>>>(pred, align, lens, row_mse, B, T);
    dploss_reduce_kernel<<<1, 1024, 0, stream>>>(row_mse, out, B);
}